// Round 1
// 103.441 us; speedup vs baseline: 1.0423x; 1.0423x over previous
//
#include <hip/hip_runtime.h>

// Problem constants (fixed by setup_inputs): bs=8, m=4096, T=32, E=65536
#define M      4096
#define TT     32
#define BS     8
#define EE     65536
#define NROWS  (BS * M)                   // 32768
#define SLOTS  64                         // hash slots per row (load ~27%)
#define NBLK   (NROWS / 8)                // compute grid = 4096 blocks

// ws layout: [slots 8 MB][partials 16 KB]
#define SLOT_BYTES ((size_t)NROWS * SLOTS * 4)
#define PART_BYTES ((size_t)NBLK * 4)
#define WS_NEED    (SLOT_BYTES + PART_BYTES)

// ---------------- Fast path ----------------

// One edge per thread (max TLP). Open-addressed per-row hash with atomicCAS:
// sentinel 0, value tgt+1, linear probe from tgt&63. Dedup happens HERE for
// free (CAS sees existing equal value -> no-op), so compute needs no dedup.
// XCD swizzle: blocks of batch b land on XCD b (2048 blocks, 256/batch).
__global__ __launch_bounds__(256) void build_slots(const int* __restrict__ coo,
                                                   unsigned int* __restrict__ slots) {
    const int lb = ((blockIdx.x & 7) << 8) | (blockIdx.x >> 3);  // bijective, 2048 blocks
    int idx = lb * 256 + threadIdx.x;             // [0, BS*EE)
    int b = idx >> 16;
    int e = idx & (EE - 1);
    const int* base = coo + (size_t)b * 2 * EE;
    int src = base[e] & (M - 1);
    int tgt = base[EE + e] & (M - 1);
    unsigned int* row = slots + ((size_t)(b * M + src) << 6);
    unsigned int val = (unsigned int)tgt + 1u;
    int s = tgt & (SLOTS - 1);
    #pragma unroll 1
    for (int probe = 0; probe < SLOTS; ++probe) {  // bounded; table load ~27%
        unsigned int old = atomicCAS(&row[s], 0u, val);
        if (old == 0u || old == val) break;        // claimed, or dup -> done
        s = (s + 1) & (SLOTS - 1);
    }
}

// One 32-lane group per row (lane = t = column). Lane k holds slots[k] and
// slots[k+32]. NEW: ballot-compact the ~16 occupied slots (of 64) into LDS,
// then a uniform count loop with uint4 LDS broadcasts -> 4 independent
// gathers in flight, zero dead gathers (was 64 unconditional gathers/row).
// XCD swizzle: 512-block chunks -> batch b resident in XCD b's L2 (512 KB).
__global__ __launch_bounds__(256) void compute_slots(const float* __restrict__ y,
                                                     const unsigned int* __restrict__ slots,
                                                     float* __restrict__ partials) {
    __shared__ float wsum[4];
    __shared__ __align__(16) unsigned int sl[8][64];
    const int tid = threadIdx.x;
    const int t = tid & 31;                        // column t
    const int grp = tid >> 5;                      // 8 groups/block
    const int lb = ((blockIdx.x & 7) << 9) | (blockIdx.x >> 3);  // bijective, 4096 blocks
    const int row = lb * 8 + grp;                  // [0, NROWS)
    const int b = row >> 12;
    const int i = row & (M - 1);

    const float* yb = y + (size_t)b * M * TT;
    const unsigned int* rs = slots + ((size_t)row << 6);
    unsigned int s0 = rs[t];                       // coalesced 128 B per group
    unsigned int s1 = rs[t + 32];

    // Per-group (half-wave) occupancy masks and prefix-sum compaction.
    unsigned long long bal0 = __ballot(s0 != 0u);
    unsigned long long bal1 = __ballot(s1 != 0u);
    const unsigned int sh = tid & 32;              // which half of the wave
    const unsigned int m0 = (unsigned int)(bal0 >> sh);
    const unsigned int m1 = (unsigned int)(bal1 >> sh);
    const unsigned int lt = (1u << t) - 1u;        // lanes-below-me mask (t<=31)
    const int c0 = __popc(m0);
    const int cnt = c0 + __popc(m1);               // occupied slots this row (~16 avg)
    if (s0) sl[grp][__popc(m0 & lt)] = s0;
    if (s1) sl[grp][c0 + __popc(m1 & lt)] = s1;
    __builtin_amdgcn_wave_barrier();               // order LDS write -> read in-wave

    float acc = yb[i * TT + t];                    // identity (eye) term
    float ynext = (t < 31) ? yb[i * TT + t + 1] : 0.0f;

    int k = 0;
    for (; k + 4 <= cnt; k += 4) {
        const uint4 j4 = *(const uint4*)&sl[grp][k];   // broadcast read, 16B aligned
        float v0 = yb[((int)j4.x - 1) * TT + t];       // 4 independent coalesced gathers
        float v1 = yb[((int)j4.y - 1) * TT + t];
        float v2 = yb[((int)j4.z - 1) * TT + t];
        float v3 = yb[((int)j4.w - 1) * TT + t];
        acc += v0; acc += v1; acc += v2; acc += v3;
    }
    for (; k < cnt; ++k) {
        acc += yb[((int)sl[grp][k] - 1) * TT + t];
    }

    float v = (t < 31) ? fmaxf(ynext - acc, 0.0f) : 0.0f;
    #pragma unroll
    for (int off = 32; off; off >>= 1) v += __shfl_down(v, off, 64);

    if ((tid & 63) == 0) wsum[tid >> 6] = v;
    __syncthreads();
    if (tid == 0) partials[blockIdx.x] = wsum[0] + wsum[1] + wsum[2] + wsum[3];
}

// Single block sums the 4096 partials. No atomics anywhere.
__global__ __launch_bounds__(1024) void reduce_partials(const float* __restrict__ p,
                                                        float* __restrict__ out) {
    const int tid = threadIdx.x;
    float s = 0.0f;
    for (int k = tid; k < NBLK; k += 1024) s += p[k];
    #pragma unroll
    for (int off = 32; off; off >>= 1) s += __shfl_down(s, off, 64);
    __shared__ float ws[16];
    if ((tid & 63) == 0) ws[tid >> 6] = s;
    __syncthreads();
    if (tid == 0) {
        float tot = 0.0f;
        #pragma unroll
        for (int k = 0; k < 16; ++k) tot += ws[k];
        out[0] = tot;
    }
}

// ---------------- Fallback (R3): LDS bitmap, no scratch ----------------
#define WPR    128
#define ROWS   64
#define NCHUNK (M / ROWS)

__global__ __launch_bounds__(256) void nil_reg_lds(const float* __restrict__ y,
                                                   const int* __restrict__ coo,
                                                   float* __restrict__ out) {
    __shared__ unsigned int bm[ROWS * WPR];
    const int tid = threadIdx.x;
    const int b = blockIdx.x / NCHUNK;
    const int chunk = blockIdx.x % NCHUNK;
    const int row0 = chunk * ROWS;
    for (int i = tid; i < ROWS * WPR; i += 256) bm[i] = 0;
    __syncthreads();
    const int* base = coo + (size_t)b * 2 * EE;
    for (int e = tid; e < EE; e += 256) {
        int src = base[e] & (M - 1);
        int tgt = base[EE + e] & (M - 1);
        int r = src - row0;
        if ((unsigned)r < (unsigned)ROWS)
            atomicOr(&bm[r * WPR + (tgt >> 5)], 1u << (tgt & 31));
    }
    __syncthreads();
    const float* yb = y + (size_t)b * M * TT;
    const int t = tid & 31;
    const int grp = tid >> 5;
    float total = 0.0f;
    for (int r = grp; r < ROWS; r += 8) {
        int i = row0 + r;
        float acc = yb[i * TT + t];
        float ynext = (t < 31) ? yb[i * TT + t + 1] : 0.0f;
        const uint4* rwp = (const uint4*)&bm[r * WPR];
        for (int w4 = 0; w4 < WPR / 4; ++w4) {
            uint4 bw = rwp[w4];
            int jb = w4 * 128;
            unsigned int w;
            w = bw.x; while (w) { int j = __ffs(w) - 1; w &= w - 1; acc += yb[(jb +      j) * TT + t]; }
            w = bw.y; while (w) { int j = __ffs(w) - 1; w &= w - 1; acc += yb[(jb + 32 + j) * TT + t]; }
            w = bw.z; while (w) { int j = __ffs(w) - 1; w &= w - 1; acc += yb[(jb + 64 + j) * TT + t]; }
            w = bw.w; while (w) { int j = __ffs(w) - 1; w &= w - 1; acc += yb[(jb + 96 + j) * TT + t]; }
        }
        if (t < 31) total += fmaxf(ynext - acc, 0.0f);
    }
    #pragma unroll
    for (int off = 32; off; off >>= 1) total += __shfl_down(total, off, 64);
    if ((tid & 63) == 0) atomicAdd(out, total);
}

extern "C" void kernel_launch(void* const* d_in, const int* in_sizes, int n_in,
                              void* d_out, int out_size, void* d_ws, size_t ws_size,
                              hipStream_t stream) {
    const float* y = (const float*)d_in[0];     // (BS*M, TT) f32
    const int* coo = (const int*)d_in[1];       // (BS, 2, EE) delivered as int32
    float* out = (float*)d_out;

    if (ws_size >= WS_NEED) {
        char* ws = (char*)d_ws;
        unsigned int* slots = (unsigned int*)ws;
        float* partials = (float*)(ws + SLOT_BYTES);
        hipMemsetAsync(slots, 0, SLOT_BYTES, stream);   // 8 MB sentinel init
        build_slots<<<(BS * EE) / 256, 256, 0, stream>>>(coo, slots);
        compute_slots<<<NBLK, 256, 0, stream>>>(y, slots, partials);
        reduce_partials<<<1, 1024, 0, stream>>>(partials, out);
    } else {
        hipMemsetAsync(out, 0, sizeof(float), stream);
        nil_reg_lds<<<BS * NCHUNK, 256, 0, stream>>>(y, coo, out);
    }
}